// Round 1
// baseline (3071.180 us; speedup 1.0000x reference)
//
#include <hip/hip_runtime.h>
#include <math.h>

// LipsNet: B=8192, D_IN=256, H=256, D_OUT=64
// out[b,:] = tanh(softplus(k) * f(x_b) / (||J_b||_F + 1e-4))
// J_b = W3 * D2(b) * W2 * D1(b) * W1   (ReLU masks per sample)
//
// One workgroup (256 threads) per sample.
// GEMM1: A[64,256] = (W3 .* r2) @ W2   -> acc in regs, thread t owns column t
// GEMM2: M[64,256] = (A .* r1) @ W1    -> thread t owns column t of M
// S = sum(M^2) -> block reduce -> output.

constexpr int DIN  = 256;
constexpr int HDIM = 256;
constexpr int DOUT = 64;

__global__ __launch_bounds__(256, 2) void lipsnet_kernel(
    const float* __restrict__ x,
    const float* __restrict__ W1, const float* __restrict__ b1,
    const float* __restrict__ W2, const float* __restrict__ b2,
    const float* __restrict__ W3, const float* __restrict__ b3,
    const float* __restrict__ kp,
    float* __restrict__ out)
{
    __shared__ float xs[DIN];
    __shared__ float h1s[HDIM];     // relu'd h1 (r1 mask = h1s > 0)
    __shared__ float h2s[HDIM];     // relu'd h2
    __shared__ float r2s[HDIM];     // r2 mask as float 0/1
    __shared__ float fparts[256];
    __shared__ float fs[DOUT];
    __shared__ float skip1[64];     // per-d4 activity of r2 (GEMM1 skip)
    __shared__ float skip2[64];     // per-c4 activity of r1 (GEMM2 skip)
    __shared__ float wsum[4];
    __shared__ __align__(16) float Vs[DOUT][HDIM];   // V = A .* r1, 64 KB

    const int b = blockIdx.x;
    const int t = threadIdx.x;

    xs[t] = x[(size_t)b * DIN + t];
    __syncthreads();

    // ---- h1 = relu(W1 @ x + b1); thread t computes row t
    float acc = b1[t];
    {
        const float* w = W1 + t * DIN;
        #pragma unroll 8
        for (int d = 0; d < DIN; d += 4) {
            float4 wv = *(const float4*)(w + d);
            acc = fmaf(wv.x, xs[d + 0], acc);
            acc = fmaf(wv.y, xs[d + 1], acc);
            acc = fmaf(wv.z, xs[d + 2], acc);
            acc = fmaf(wv.w, xs[d + 3], acc);
        }
    }
    const float h1v = fmaxf(acc, 0.0f);
    h1s[t] = h1v;
    __syncthreads();

    // ---- h2 = relu(W2 @ h1 + b2); thread t computes row t
    acc = b2[t];
    {
        const float* w = W2 + t * HDIM;
        #pragma unroll 8
        for (int d = 0; d < HDIM; d += 4) {
            float4 wv = *(const float4*)(w + d);
            acc = fmaf(wv.x, h1s[d + 0], acc);
            acc = fmaf(wv.y, h1s[d + 1], acc);
            acc = fmaf(wv.z, h1s[d + 2], acc);
            acc = fmaf(wv.w, h1s[d + 3], acc);
        }
    }
    h2s[t] = fmaxf(acc, 0.0f);
    r2s[t] = (acc > 0.0f) ? 1.0f : 0.0f;
    __syncthreads();

    if (t < 64) {
        skip1[t] = r2s[4 * t] + r2s[4 * t + 1] + r2s[4 * t + 2] + r2s[4 * t + 3];
        skip2[t] = h1s[4 * t] + h1s[4 * t + 1] + h1s[4 * t + 2] + h1s[4 * t + 3];
    }

    // ---- f = W3 @ h2 + b3 (distributed: output j = t&63, quarter q = t>>6)
    {
        const int j = t & 63, q = t >> 6;
        const float* w = W3 + j * HDIM + q * 64;
        const float* h = h2s + q * 64;
        float fp = 0.0f;
        #pragma unroll
        for (int d = 0; d < 64; d += 4) {
            float4 wv = *(const float4*)(w + d);
            fp = fmaf(wv.x, h[d + 0], fp);
            fp = fmaf(wv.y, h[d + 1], fp);
            fp = fmaf(wv.z, h[d + 2], fp);
            fp = fmaf(wv.w, h[d + 3], fp);
        }
        fparts[t] = fp;
    }
    __syncthreads();
    if (t < 64) fs[t] = b3[t] + fparts[t] + fparts[t + 64] + fparts[t + 128] + fparts[t + 192];
    __syncthreads();   // fs, skip1, skip2 visible to all

    // ---- GEMM1: A[j, t] = sum_d W3[j,d] * r2[d] * W2[d, t]
    float a1[DOUT];
    #pragma unroll
    for (int j = 0; j < DOUT; ++j) a1[j] = 0.0f;

    #pragma unroll 1
    for (int d0 = 0; d0 < HDIM; d0 += 4) {
        if (skip1[d0 >> 2] == 0.0f) continue;   // wave-uniform branch
        const float w2v0 = r2s[d0 + 0] * W2[(d0 + 0) * HDIM + t];
        const float w2v1 = r2s[d0 + 1] * W2[(d0 + 1) * HDIM + t];
        const float w2v2 = r2s[d0 + 2] * W2[(d0 + 2) * HDIM + t];
        const float w2v3 = r2s[d0 + 3] * W2[(d0 + 3) * HDIM + t];
        #pragma unroll
        for (int j = 0; j < DOUT; ++j) {
            float4 w3 = *(const float4*)(W3 + j * HDIM + d0);  // wave-uniform -> scalar load
            a1[j] = fmaf(w3.x, w2v0, a1[j]);
            a1[j] = fmaf(w3.y, w2v1, a1[j]);
            a1[j] = fmaf(w3.z, w2v2, a1[j]);
            a1[j] = fmaf(w3.w, w2v3, a1[j]);
        }
    }

    // ---- V = A .* r1  (column t masked by r1[t]); write column to LDS
    {
        const float r1t = (h1v > 0.0f) ? 1.0f : 0.0f;
        #pragma unroll
        for (int j = 0; j < DOUT; ++j) Vs[j][t] = a1[j] * r1t;   // stride-1 across lanes
    }
    __syncthreads();

    // ---- GEMM2: M[j, t] = sum_c V[j,c] * W1[c, t]
    float a2[DOUT];
    #pragma unroll
    for (int j = 0; j < DOUT; ++j) a2[j] = 0.0f;

    #pragma unroll 1
    for (int c0 = 0; c0 < HDIM; c0 += 4) {
        if (skip2[c0 >> 2] == 0.0f) continue;   // wave-uniform branch
        const float w10 = W1[(c0 + 0) * DIN + t];
        const float w11 = W1[(c0 + 1) * DIN + t];
        const float w12 = W1[(c0 + 2) * DIN + t];
        const float w13 = W1[(c0 + 3) * DIN + t];
        #pragma unroll
        for (int j = 0; j < DOUT; ++j) {
            float4 v = *(const float4*)&Vs[j][c0];   // LDS broadcast read
            a2[j] = fmaf(v.x, w10, a2[j]);
            a2[j] = fmaf(v.y, w11, a2[j]);
            a2[j] = fmaf(v.z, w12, a2[j]);
            a2[j] = fmaf(v.w, w13, a2[j]);
        }
    }

    // ---- S = sum_j sum_e M[j,e]^2
    float s = 0.0f;
    #pragma unroll
    for (int j = 0; j < DOUT; ++j) s = fmaf(a2[j], a2[j], s);

    #pragma unroll
    for (int off = 32; off > 0; off >>= 1) s += __shfl_down(s, off, 64);
    if ((t & 63) == 0) wsum[t >> 6] = s;
    __syncthreads();

    if (t < DOUT) {
        const float S = wsum[0] + wsum[1] + wsum[2] + wsum[3];
        const float kv = kp[0];
        const float ksp = fmaxf(kv, 0.0f) + log1pf(expf(-fabsf(kv)));  // softplus
        const float jn = sqrtf(S) + 1e-4f;
        out[(size_t)b * DOUT + t] = tanhf(ksp * fs[t] / jn);
    }
}

extern "C" void kernel_launch(void* const* d_in, const int* in_sizes, int n_in,
                              void* d_out, int out_size, void* d_ws, size_t ws_size,
                              hipStream_t stream) {
    const float* x  = (const float*)d_in[0];
    const float* W1 = (const float*)d_in[1];
    const float* b1 = (const float*)d_in[2];
    const float* W2 = (const float*)d_in[3];
    const float* b2 = (const float*)d_in[4];
    const float* W3 = (const float*)d_in[5];
    const float* b3 = (const float*)d_in[6];
    const float* kp = (const float*)d_in[7];
    float* out = (float*)d_out;

    lipsnet_kernel<<<8192, 256, 0, stream>>>(x, W1, b1, W2, b2, W3, b3, kp, out);
}

// Round 2
// 274.221 us; speedup vs baseline: 11.1996x; 11.1996x over previous
//
#include <hip/hip_runtime.h>
#include <math.h>

// LipsNet MFMA rewrite. B=8192, D_IN=256, H=256, D_OUT=64.
// K0: swizzle W2,W1 -> bf16 MFMA B-fragment order in ws; W3 -> bf16 row-major.
// K1: fp32 forward (16 samples/block), writes r1,r2 masks (u8) + f (fp32) to ws.
// K2: per-sample Jacobian via 16x16x32 bf16 MFMA:
//     A1 = (W3 .* r2) @ W2 ; M = (A1 .* r1) @ W1 ; out = tanh(softplus(k)*f/(||M||_F+eps))
//
// MFMA 16x16x32 layouts (guide §3, m89/m118 verified):
//   A[m][k]: m = lane&15, k = (lane>>4)*8 + i   (i = 0..7 within the 8 bf16)
//   B[k][n]: n = lane&15, k = (lane>>4)*8 + i
//   C/D:     col = lane&15, row = (lane>>4)*4 + reg

typedef float  f32x4  __attribute__((ext_vector_type(4)));
typedef short  bf16x8 __attribute__((ext_vector_type(8)));
typedef unsigned int   uint;
typedef unsigned short ushort;
typedef unsigned char  uchar;
typedef uint   u32x4  __attribute__((ext_vector_type(4)));

// ws byte offsets
#define W2F_OFF 0u         // 16cb x 8ks x 64lane x 8 bf16 = 131072 B
#define W1F_OFF 131072u    // 131072 B
#define W3B_OFF 262144u    // 64x256 bf16 = 32768 B
#define F_OFF   294912u    // 8192x64 fp32 = 2097152 B
#define R1_OFF  2392064u   // 8192x256 u8 = 2097152 B
#define R2_OFF  4489216u   // 8192x256 u8 = 2097152 B
// total 6586368 B

__device__ __forceinline__ ushort f2bf(float f) {
    uint u = __builtin_bit_cast(uint, f);
    u += 0x7FFFu + ((u >> 16) & 1u);          // RNE
    return (ushort)(u >> 16);
}

// ---------------- K0: weight prep ----------------
__global__ __launch_bounds__(256) void k0_prep(
    const float* __restrict__ W1, const float* __restrict__ W2,
    const float* __restrict__ W3, char* __restrict__ ws)
{
    const int id = blockIdx.x * 256 + threadIdx.x;
    if (id < 16384) {
        // B-fragment swizzle: frag(cb,ks,lane,i) = W[ks*32+(lane>>4)*8+i][cb*16+(lane&15)]
        const float* M = (id < 8192) ? W2 : W1;
        u32x4* dst = (u32x4*)(ws + ((id < 8192) ? W2F_OFF : W1F_OFF));
        const int u = id & 8191;
        const int cb = u >> 9, ks = (u >> 6) & 7, l = u & 63;
        const int n  = cb * 16 + (l & 15);
        const int k0 = ks * 32 + (l >> 4) * 8;
        ushort h[8];
        #pragma unroll
        for (int i = 0; i < 8; ++i) h[i] = f2bf(M[(k0 + i) * 256 + n]);
        u32x4 v;
        v.x = (uint)h[0] | ((uint)h[1] << 16);
        v.y = (uint)h[2] | ((uint)h[3] << 16);
        v.z = (uint)h[4] | ((uint)h[5] << 16);
        v.w = (uint)h[6] | ((uint)h[7] << 16);
        dst[u] = v;
    } else if (id < 18432) {
        const int v0 = id - 16384;               // 0..2047, 8 elems each
        u32x4* dst = (u32x4*)(ws + W3B_OFF);
        ushort h[8];
        #pragma unroll
        for (int i = 0; i < 8; ++i) h[i] = f2bf(W3[v0 * 8 + i]);
        u32x4 v;
        v.x = (uint)h[0] | ((uint)h[1] << 16);
        v.y = (uint)h[2] | ((uint)h[3] << 16);
        v.z = (uint)h[4] | ((uint)h[5] << 16);
        v.w = (uint)h[6] | ((uint)h[7] << 16);
        dst[v0] = v;
    }
}

// ---------------- K1: fp32 forward, 16 samples/block ----------------
__device__ __forceinline__ void layer256(
    const f32x4* __restrict__ in, const f32x4* __restrict__ Wm,
    const float* __restrict__ bias, int gi, int n0, float acc[4][4])
{
    #pragma unroll
    for (int j = 0; j < 4; ++j) {
        const float bv = bias[n0 + j];
        #pragma unroll
        for (int gg = 0; gg < 4; ++gg) acc[gg][j] = bv;
    }
    #pragma unroll 4
    for (int dq = 0; dq < 64; ++dq) {
        f32x4 a[4], w[4];
        #pragma unroll
        for (int gg = 0; gg < 4; ++gg) a[gg] = in[(gi + gg) * 65 + dq];
        #pragma unroll
        for (int j = 0; j < 4; ++j) w[j] = Wm[(n0 + j) * 64 + dq];
        #pragma unroll
        for (int gg = 0; gg < 4; ++gg)
            #pragma unroll
            for (int j = 0; j < 4; ++j) {
                float s = acc[gg][j];
                s = fmaf(a[gg].x, w[j].x, s);
                s = fmaf(a[gg].y, w[j].y, s);
                s = fmaf(a[gg].z, w[j].z, s);
                s = fmaf(a[gg].w, w[j].w, s);
                acc[gg][j] = s;
            }
    }
}

__global__ __launch_bounds__(256) void k1_forward(
    const float* __restrict__ x,
    const float* __restrict__ W1, const float* __restrict__ b1,
    const float* __restrict__ W2, const float* __restrict__ b2,
    const float* __restrict__ W3, const float* __restrict__ b3,
    char* __restrict__ ws)
{
    __shared__ f32x4 xsv[1040];   // [16][65] row-major, stride 65*16B
    __shared__ f32x4 h1v[1040];
    __shared__ f32x4 h2v[1040];
    float* h1f = (float*)h1v;
    float* h2f = (float*)h2v;
    float* fws = (float*)(ws + F_OFF);
    uchar* r1g = (uchar*)(ws + R1_OFF);
    uchar* r2g = (uchar*)(ws + R2_OFF);

    const int t = threadIdx.x;
    const int g0 = blockIdx.x * 16;
    const f32x4* X4 = (const f32x4*)x;

    #pragma unroll
    for (int i = 0; i < 4; ++i) {
        const int fid = t + 256 * i;
        const int g = fid >> 6, dq = fid & 63;
        xsv[g * 65 + dq] = X4[(size_t)(g0 + g) * 64 + dq];
    }
    __syncthreads();

    const int gi = (t & 3) * 4;
    const int n0 = (t >> 2) * 4;
    const f32x4* W1_4 = (const f32x4*)W1;
    const f32x4* W2_4 = (const f32x4*)W2;
    const f32x4* W3_4 = (const f32x4*)W3;

    float acc[4][4];
    // layer 1
    layer256(xsv, W1_4, b1, gi, n0, acc);
    #pragma unroll
    for (int gg = 0; gg < 4; ++gg)
        #pragma unroll
        for (int j = 0; j < 4; ++j) {
            const float v = acc[gg][j];
            r1g[(size_t)(g0 + gi + gg) * 256 + (n0 + j)] = (uchar)(v > 0.0f);
            h1f[(gi + gg) * 260 + (n0 + j)] = fmaxf(v, 0.0f);
        }
    __syncthreads();
    // layer 2
    layer256(h1v, W2_4, b2, gi, n0, acc);
    #pragma unroll
    for (int gg = 0; gg < 4; ++gg)
        #pragma unroll
        for (int j = 0; j < 4; ++j) {
            const float v = acc[gg][j];
            r2g[(size_t)(g0 + gi + gg) * 256 + (n0 + j)] = (uchar)(v > 0.0f);
            h2f[(gi + gg) * 260 + (n0 + j)] = fmaxf(v, 0.0f);
        }
    __syncthreads();
    // layer 3: j0 = t>>2 (0..63), 4 samples each
    {
        const int j0 = t >> 2;
        float a3[4];
        #pragma unroll
        for (int gg = 0; gg < 4; ++gg) a3[gg] = b3[j0];
        #pragma unroll 4
        for (int dq = 0; dq < 64; ++dq) {
            const f32x4 wv = W3_4[j0 * 64 + dq];
            #pragma unroll
            for (int gg = 0; gg < 4; ++gg) {
                const f32x4 a = h2v[(gi + gg) * 65 + dq];
                float s = a3[gg];
                s = fmaf(a.x, wv.x, s);
                s = fmaf(a.y, wv.y, s);
                s = fmaf(a.z, wv.z, s);
                s = fmaf(a.w, wv.w, s);
                a3[gg] = s;
            }
        }
        #pragma unroll
        for (int gg = 0; gg < 4; ++gg)
            fws[(size_t)(g0 + gi + gg) * 64 + j0] = a3[gg];
    }
}

// ---------------- K2: per-sample Jacobian norm + output ----------------
__global__ __launch_bounds__(256) void k2_jac(
    const char* __restrict__ ws, const float* __restrict__ kp,
    float* __restrict__ out)
{
    __shared__ u32x4 AbufV[2048];          // 32 KB, A-fragment order: slot=(rb*8+ks)*64+lane
    __shared__ uint  r1sw[64], r2sw[64];   // 256 mask bytes each
    __shared__ float red[4];

    const int b = blockIdx.x, t = threadIdx.x;
    const int w = t >> 6, l = t & 63;

    if (t < 64) {
        r1sw[t] = ((const uint*)(ws + R1_OFF))[(size_t)b * 64 + t];
        r2sw[t] = ((const uint*)(ws + R2_OFF))[(size_t)b * 64 + t];
    }
    __syncthreads();

    // Phase A: Abuf = (W3 .* r2) in A-fragment layout
    {
        const u32x4* W3b = (const u32x4*)(ws + W3B_OFF);   // row j = 32 x 16B units
        const int j = t >> 2, c0 = (t & 3) * 64;
        const int rb = j >> 4, lo = j & 15;
        #pragma unroll
        for (int ch = 0; ch < 8; ++ch) {
            const int c = c0 + ch * 8;
            u32x4 v = W3b[j * 32 + (c >> 3)];
            const uint bm0 = r2sw[c >> 2], bm1 = r2sw[(c >> 2) + 1];
            const uint q0 = ((bm0 & 0xFFu)       ? 0xFFFFu : 0u) | ((bm0 & 0xFF00u)      ? 0xFFFF0000u : 0u);
            const uint q1 = ((bm0 & 0xFF0000u)   ? 0xFFFFu : 0u) | ((bm0 & 0xFF000000u)  ? 0xFFFF0000u : 0u);
            const uint q2 = ((bm1 & 0xFFu)       ? 0xFFFFu : 0u) | ((bm1 & 0xFF00u)      ? 0xFFFF0000u : 0u);
            const uint q3 = ((bm1 & 0xFF0000u)   ? 0xFFFFu : 0u) | ((bm1 & 0xFF000000u)  ? 0xFFFF0000u : 0u);
            v.x &= q0; v.y &= q1; v.z &= q2; v.w &= q3;
            const int ks = c >> 5, hi = (c >> 3) & 3;
            AbufV[(rb * 8 + ks) * 64 + hi * 16 + lo] = v;
        }
    }
    __syncthreads();

    const bf16x8* Ab  = (const bf16x8*)AbufV;
    const bf16x8* BW2 = (const bf16x8*)(ws + W2F_OFF);
    const bf16x8* BW1 = (const bf16x8*)(ws + W1F_OFF);

    // GEMM1: acc[cbl][rb] over col-blocks cb = 4w+cbl, row-blocks rb
    f32x4 acc[4][4];
    #pragma unroll
    for (int i = 0; i < 4; ++i)
        #pragma unroll
        for (int j = 0; j < 4; ++j) acc[i][j] = (f32x4){0.f, 0.f, 0.f, 0.f};

    for (int ks = 0; ks < 8; ++ks) {
        bf16x8 a[4];
        #pragma unroll
        for (int rb = 0; rb < 4; ++rb) a[rb] = Ab[(rb * 8 + ks) * 64 + l];
        #pragma unroll
        for (int cbl = 0; cbl < 4; ++cbl) {
            const bf16x8 bb = BW2[((4 * w + cbl) * 8 + ks) * 64 + l];
            #pragma unroll
            for (int rb = 0; rb < 4; ++rb)
                acc[cbl][rb] = __builtin_amdgcn_mfma_f32_16x16x32_bf16(a[rb], bb, acc[cbl][rb], 0, 0, 0);
        }
    }
    __syncthreads();   // all Abuf reads complete

    // Phase C: V = acc .* r1 -> bf16, scatter into A-fragment layout for GEMM2
    {
        const uchar* r1b = (const uchar*)r1sw;
        ushort* Ah = (ushort*)AbufV;
        #pragma unroll
        for (int cbl = 0; cbl < 4; ++cbl) {
            const int e = (4 * w + cbl) * 16 + (l & 15);   // column of A1 = k-index of GEMM2
            const float m = (float)r1b[e];
            const int ks2 = e >> 5, hi2 = (e >> 3) & 3, i2 = e & 7;
            #pragma unroll
            for (int rb = 0; rb < 4; ++rb)
                #pragma unroll
                for (int r = 0; r < 4; ++r) {
                    const int lo2 = (l >> 4) * 4 + r;      // row j & 15
                    Ah[((rb * 8 + ks2) * 64 + hi2 * 16 + lo2) * 8 + i2] = f2bf(acc[cbl][rb][r] * m);
                }
        }
    }
    __syncthreads();

    // GEMM2: M = V @ W1
    f32x4 acc2[4][4];
    #pragma unroll
    for (int i = 0; i < 4; ++i)
        #pragma unroll
        for (int j = 0; j < 4; ++j) acc2[i][j] = (f32x4){0.f, 0.f, 0.f, 0.f};

    for (int ks = 0; ks < 8; ++ks) {
        bf16x8 a[4];
        #pragma unroll
        for (int rb = 0; rb < 4; ++rb) a[rb] = Ab[(rb * 8 + ks) * 64 + l];
        #pragma unroll
        for (int cbl = 0; cbl < 4; ++cbl) {
            const bf16x8 bb = BW1[((4 * w + cbl) * 8 + ks) * 64 + l];
            #pragma unroll
            for (int rb = 0; rb < 4; ++rb)
                acc2[cbl][rb] = __builtin_amdgcn_mfma_f32_16x16x32_bf16(a[rb], bb, acc2[cbl][rb], 0, 0, 0);
        }
    }

    // Reduce ||M||_F^2
    float s = 0.0f;
    #pragma unroll
    for (int cbl = 0; cbl < 4; ++cbl)
        #pragma unroll
        for (int rb = 0; rb < 4; ++rb) {
            const f32x4 v = acc2[cbl][rb];
            s = fmaf(v.x, v.x, s);
            s = fmaf(v.y, v.y, s);
            s = fmaf(v.z, v.z, s);
            s = fmaf(v.w, v.w, s);
        }
    #pragma unroll
    for (int off = 32; off > 0; off >>= 1) s += __shfl_down(s, off, 64);
    if (l == 0) red[w] = s;
    __syncthreads();

    if (t < 64) {
        const float S = red[0] + red[1] + red[2] + red[3];
        const float* fws = (const float*)(ws + F_OFF);
        const float kv = kp[0];
        const float ksp = fmaxf(kv, 0.0f) + log1pf(expf(-fabsf(kv)));  // softplus
        const float jn = sqrtf(S) + 1e-4f;
        out[(size_t)b * 64 + t] = tanhf(ksp * fws[(size_t)b * 64 + t] / jn);
    }
}

extern "C" void kernel_launch(void* const* d_in, const int* in_sizes, int n_in,
                              void* d_out, int out_size, void* d_ws, size_t ws_size,
                              hipStream_t stream) {
    const float* x  = (const float*)d_in[0];
    const float* W1 = (const float*)d_in[1];
    const float* b1 = (const float*)d_in[2];
    const float* W2 = (const float*)d_in[3];
    const float* b2 = (const float*)d_in[4];
    const float* W3 = (const float*)d_in[5];
    const float* b3 = (const float*)d_in[6];
    const float* kp = (const float*)d_in[7];
    char* ws = (char*)d_ws;

    k0_prep<<<72, 256, 0, stream>>>(W1, W2, W3, ws);
    k1_forward<<<512, 256, 0, stream>>>(x, W1, b1, W2, b2, W3, b3, ws);
    k2_jac<<<8192, 256, 0, stream>>>(ws, kp, (float*)d_out);
}

// Round 4
// 241.338 us; speedup vs baseline: 12.7256x; 1.1363x over previous
//
#include <hip/hip_runtime.h>
#include <math.h>

// LipsNet R4 hybrid: R2-validated fp32 forward (k1) + R3 transposed MFMA Jacobian (k2).
// B=8192, D_IN=256, H=256, D_OUT=64.
// k0: swizzle W2^T, W1^T (Jacobian A-frags) + W3 (A-frag) to bf16 in ws.
// k1: fp32 forward, 16 samples/block, writes r1,r2 masks (u8) + f (fp32) to ws.   [R2-validated]
// k2: per 2-sample block (512 thr): A1^T = W2T @ (W3 .* r2)^T ; M^T = W1T @ (A1^T .* r1);
//     out = tanh(softplus(k) * f / (||M||_F + eps)).
//
// MFMA 16x16x32 layouts (validated in R2):
//   A[m][k]: m = lane&15, k = (lane>>4)*8 + i
//   B[k][n]: n = lane&15, k = (lane>>4)*8 + i
//   C/D:     col = lane&15, row = (lane>>4)*4 + reg

typedef float  f32x4  __attribute__((ext_vector_type(4)));
typedef short  bf16x8 __attribute__((ext_vector_type(8)));
typedef unsigned int   uint;
typedef unsigned short ushort;
typedef unsigned char  uchar;
typedef uint   u32x4  __attribute__((ext_vector_type(4)));
typedef uint   u32x2  __attribute__((ext_vector_type(2)));

// ws byte offsets
#define W2TA_OFF 0u        // 16rb x 8ks x 64l x 16B = 131072
#define W1TA_OFF 131072u   // 131072
#define W3A_OFF  262144u   // 4rb x 8ks x 64l x 16B = 32768
#define F_OFF    294912u   // 8192x64 fp32 = 2097152
#define R1_OFF   2392064u  // 8192x256 u8 = 2097152
#define R2_OFF   4489216u  // 2097152
// total 6586368 B

__device__ __forceinline__ ushort f2bf(float f) {
    uint u = __builtin_bit_cast(uint, f);
    u += 0x7FFFu + ((u >> 16) & 1u);          // RNE
    return (ushort)(u >> 16);
}
// halfword and-mask from two mask bytes of u at bit positions sh, sh+8
__device__ __forceinline__ uint hm2(uint u, int sh) {
    return (((u >> sh) & 0xFFu)   ? 0xFFFFu     : 0u) |
           (((u >> sh) & 0xFF00u) ? 0xFFFF0000u : 0u);
}

// ---------------- k0: weight prep ----------------
__global__ __launch_bounds__(256) void k0_prep(
    const float* __restrict__ W1, const float* __restrict__ W2,
    const float* __restrict__ W3, char* __restrict__ ws)
{
    const int id = blockIdx.x * 256 + threadIdx.x;
    if (id >= 18432) return;
    const int grp = id >> 13;          // 0,1, 2(partial: 2048)
    const int fid = id & 8191;
    const int l = fid & 63, ks = (fid >> 6) & 7, rb = fid >> 9;
    const int m = l & 15, q = l >> 4;
    const int k0 = ks * 32 + q * 8;
    ushort h[8];
    uint dstoff;
    if (grp == 0) {          // W2TA: A[m][k] = W2[k][rb*16+m]  (transposed gather)
        const int e = rb * 16 + m;
        #pragma unroll
        for (int i = 0; i < 8; ++i) h[i] = f2bf(W2[(k0 + i) * 256 + e]);
        dstoff = W2TA_OFF;
    } else if (grp == 1) {   // W1TA: A[m][k] = W1[k][rb*16+m]
        const int n = rb * 16 + m;
        #pragma unroll
        for (int i = 0; i < 8; ++i) h[i] = f2bf(W1[(k0 + i) * 256 + n]);
        dstoff = W1TA_OFF;
    } else {                 // W3A: A[m][k] = W3[rb*16+m][k]  (fid 0..2047, rb 0..3)
        const float* p = W3 + (rb * 16 + m) * 256 + k0;
        #pragma unroll
        for (int i = 0; i < 8; ++i) h[i] = f2bf(p[i]);
        dstoff = W3A_OFF;
    }
    u32x4 v;
    v.x = (uint)h[0] | ((uint)h[1] << 16);
    v.y = (uint)h[2] | ((uint)h[3] << 16);
    v.z = (uint)h[4] | ((uint)h[5] << 16);
    v.w = (uint)h[6] | ((uint)h[7] << 16);
    ((u32x4*)(ws + dstoff))[fid] = v;
}

// ---------------- k1: fp32 forward, 16 samples/block (R2-validated) ----------------
__device__ __forceinline__ void layer256(
    const f32x4* __restrict__ in, const f32x4* __restrict__ Wm,
    const float* __restrict__ bias, int gi, int n0, float acc[4][4])
{
    #pragma unroll
    for (int j = 0; j < 4; ++j) {
        const float bv = bias[n0 + j];
        #pragma unroll
        for (int gg = 0; gg < 4; ++gg) acc[gg][j] = bv;
    }
    #pragma unroll 4
    for (int dq = 0; dq < 64; ++dq) {
        f32x4 a[4], w[4];
        #pragma unroll
        for (int gg = 0; gg < 4; ++gg) a[gg] = in[(gi + gg) * 65 + dq];
        #pragma unroll
        for (int j = 0; j < 4; ++j) w[j] = Wm[(n0 + j) * 64 + dq];
        #pragma unroll
        for (int gg = 0; gg < 4; ++gg)
            #pragma unroll
            for (int j = 0; j < 4; ++j) {
                float s = acc[gg][j];
                s = fmaf(a[gg].x, w[j].x, s);
                s = fmaf(a[gg].y, w[j].y, s);
                s = fmaf(a[gg].z, w[j].z, s);
                s = fmaf(a[gg].w, w[j].w, s);
                acc[gg][j] = s;
            }
    }
}

__global__ __launch_bounds__(256) void k1_forward(
    const float* __restrict__ x,
    const float* __restrict__ W1, const float* __restrict__ b1,
    const float* __restrict__ W2, const float* __restrict__ b2,
    const float* __restrict__ W3, const float* __restrict__ b3,
    char* __restrict__ ws)
{
    __shared__ f32x4 xsv[1040];   // [16][65] row-major, stride 65*16B
    __shared__ f32x4 h1v[1040];
    __shared__ f32x4 h2v[1040];
    float* h1f = (float*)h1v;
    float* h2f = (float*)h2v;
    float* fws = (float*)(ws + F_OFF);
    uchar* r1g = (uchar*)(ws + R1_OFF);
    uchar* r2g = (uchar*)(ws + R2_OFF);

    const int t = threadIdx.x;
    const int g0 = blockIdx.x * 16;
    const f32x4* X4 = (const f32x4*)x;

    #pragma unroll
    for (int i = 0; i < 4; ++i) {
        const int fid = t + 256 * i;
        const int g = fid >> 6, dq = fid & 63;
        xsv[g * 65 + dq] = X4[(size_t)(g0 + g) * 64 + dq];
    }
    __syncthreads();

    const int gi = (t & 3) * 4;
    const int n0 = (t >> 2) * 4;
    const f32x4* W1_4 = (const f32x4*)W1;
    const f32x4* W2_4 = (const f32x4*)W2;
    const f32x4* W3_4 = (const f32x4*)W3;

    float acc[4][4];
    // layer 1
    layer256(xsv, W1_4, b1, gi, n0, acc);
    #pragma unroll
    for (int gg = 0; gg < 4; ++gg)
        #pragma unroll
        for (int j = 0; j < 4; ++j) {
            const float v = acc[gg][j];
            r1g[(size_t)(g0 + gi + gg) * 256 + (n0 + j)] = (uchar)(v > 0.0f);
            h1f[(gi + gg) * 260 + (n0 + j)] = fmaxf(v, 0.0f);
        }
    __syncthreads();
    // layer 2
    layer256(h1v, W2_4, b2, gi, n0, acc);
    #pragma unroll
    for (int gg = 0; gg < 4; ++gg)
        #pragma unroll
        for (int j = 0; j < 4; ++j) {
            const float v = acc[gg][j];
            r2g[(size_t)(g0 + gi + gg) * 256 + (n0 + j)] = (uchar)(v > 0.0f);
            h2f[(gi + gg) * 260 + (n0 + j)] = fmaxf(v, 0.0f);
        }
    __syncthreads();
    // layer 3: j0 = t>>2 (0..63), 4 samples each
    {
        const int j0 = t >> 2;
        float a3[4];
        #pragma unroll
        for (int gg = 0; gg < 4; ++gg) a3[gg] = b3[j0];
        #pragma unroll 4
        for (int dq = 0; dq < 64; ++dq) {
            const f32x4 wv = W3_4[j0 * 64 + dq];
            #pragma unroll
            for (int gg = 0; gg < 4; ++gg) {
                const f32x4 a = h2v[(gi + gg) * 65 + dq];
                float s = a3[gg];
                s = fmaf(a.x, wv.x, s);
                s = fmaf(a.y, wv.y, s);
                s = fmaf(a.z, wv.z, s);
                s = fmaf(a.w, wv.w, s);
                a3[gg] = s;
            }
        }
        #pragma unroll
        for (int gg = 0; gg < 4; ++gg)
            fws[(size_t)(g0 + gi + gg) * 64 + j0] = a3[gg];
    }
}

// ---------------- k2: Jacobian norm + output, 2 samples/block, 512 thr ----------------
__global__ __launch_bounds__(512, 4) void k2_jac(
    const char* __restrict__ ws, const float* __restrict__ kp,
    float* __restrict__ out)
{
    __shared__ char Buf[65536];            // per sample 32 KB: Bfrag1 then Vh (overlaid)
    __shared__ uint r1u[2][64], r2u[2][64];
    __shared__ float red[2][8];

    const int t = threadIdx.x, w = t >> 6, l = t & 63;
    const int m = l & 15, q = l >> 4;
    const int b = blockIdx.x;

    if (t < 128) {
        const int s = t >> 6, i = t & 63;
        r1u[s][i] = ((const uint*)(ws + R1_OFF))[(size_t)(b * 2 + s) * 64 + i];
        r2u[s][i] = ((const uint*)(ws + R2_OFF))[(size_t)(b * 2 + s) * 64 + i];
    }
    __syncthreads();

    // ---- Phase A: build Bf1[s] = (W3 .* r2_s)^T B-frags (8 frags per wave)
    {
        const u32x4* W3Av = (const u32x4*)(ws + W3A_OFF);
        u32x4* BufV = (u32x4*)Buf;
        #pragma unroll
        for (int ii = 0; ii < 8; ++ii) {
            const int id = w * 8 + ii;
            const int s = id >> 5, cb = (id >> 3) & 3, ks = id & 7;
            u32x4 v = W3Av[(cb * 8 + ks) * 64 + l];
            const int du = ks * 8 + q * 2;            // (d0>>2), d0 = ks*32+q*8
            const uint u0 = r2u[s][du], u1 = r2u[s][du + 1];
            v.x &= hm2(u0, 0);  v.y &= hm2(u0, 16);
            v.z &= hm2(u1, 0);  v.w &= hm2(u1, 16);
            BufV[s * 2048 + (cb * 8 + ks) * 64 + l] = v;
        }
    }
    __syncthreads();

    // ---- GEMM1: A1^T = W2T @ Bf1 ; wave w owns rb in {2w, 2w+1}, both samples, all cb
    f32x4 acc[2][2][4];                    // [s][rp][cb]
    #pragma unroll
    for (int s = 0; s < 2; ++s)
        #pragma unroll
        for (int rp = 0; rp < 2; ++rp)
            #pragma unroll
            for (int cb = 0; cb < 4; ++cb) acc[s][rp][cb] = (f32x4){0.f, 0.f, 0.f, 0.f};

    {
        const bf16x8* W2Tf = (const bf16x8*)(ws + W2TA_OFF);
        const bf16x8* BufF = (const bf16x8*)Buf;
        #pragma unroll
        for (int ks = 0; ks < 8; ++ks) {
            bf16x8 a[2];
            #pragma unroll
            for (int rp = 0; rp < 2; ++rp) a[rp] = W2Tf[((2 * w + rp) * 8 + ks) * 64 + l];
            #pragma unroll
            for (int s = 0; s < 2; ++s)
                #pragma unroll
                for (int cb = 0; cb < 4; ++cb) {
                    const bf16x8 bb = BufF[s * 2048 + (cb * 8 + ks) * 64 + l];
                    #pragma unroll
                    for (int rp = 0; rp < 2; ++rp)
                        acc[s][rp][cb] = __builtin_amdgcn_mfma_f32_16x16x32_bf16(a[rp], bb, acc[s][rp][cb], 0, 0, 0);
                }
        }
    }
    __syncthreads();   // all Bf1 reads done before overlay

    // ---- Phase C: Vh[s][j][e] = A1^T[e][j] * r1[e] (bf16, XOR-swizzled, b64 writes)
    {
        ushort* Vh = (ushort*)Buf;
        #pragma unroll
        for (int s = 0; s < 2; ++s)
            #pragma unroll
            for (int rp = 0; rp < 2; ++rp) {
                const int rb = 2 * w + rp;
                const int e0 = rb * 16 + q * 4;
                const uint mu = r1u[s][rb * 4 + q];
                #pragma unroll
                for (int cb = 0; cb < 4; ++cb) {
                    const f32x4 av = acc[s][rp][cb];
                    const float v0 = (mu & 0xFFu)       ? av.x : 0.f;
                    const float v1 = (mu & 0xFF00u)     ? av.y : 0.f;
                    const float v2 = (mu & 0xFF0000u)   ? av.z : 0.f;
                    const float v3 = (mu & 0xFF000000u) ? av.w : 0.f;
                    u32x2 p;
                    p.x = (uint)f2bf(v0) | ((uint)f2bf(v1) << 16);
                    p.y = (uint)f2bf(v2) | ((uint)f2bf(v3) << 16);
                    const int j = cb * 16 + m;
                    const int idx = j * 256 + (e0 ^ ((j & 7) << 3));
                    *(u32x2*)&Vh[s * 16384 + idx] = p;
                }
            }
    }
    __syncthreads();

    // ---- GEMM2: M^T = W1T @ (Vh as B) ; wave w owns rb_n in {2w, 2w+1}
    f32x4 acc2[2][2][4];
    #pragma unroll
    for (int s = 0; s < 2; ++s)
        #pragma unroll
        for (int rp = 0; rp < 2; ++rp)
            #pragma unroll
            for (int cb = 0; cb < 4; ++cb) acc2[s][rp][cb] = (f32x4){0.f, 0.f, 0.f, 0.f};

    {
        const bf16x8* W1Tf = (const bf16x8*)(ws + W1TA_OFF);
        const ushort* Vh = (const ushort*)Buf;
        #pragma unroll
        for (int ks = 0; ks < 8; ++ks) {
            bf16x8 a[2];
            #pragma unroll
            for (int rp = 0; rp < 2; ++rp) a[rp] = W1Tf[((2 * w + rp) * 8 + ks) * 64 + l];
            const int c0 = ks * 32 + q * 8;
            #pragma unroll
            for (int s = 0; s < 2; ++s)
                #pragma unroll
                for (int cb = 0; cb < 4; ++cb) {
                    const int j = cb * 16 + m;
                    const bf16x8 bb = *(const bf16x8*)&Vh[s * 16384 + j * 256 + (c0 ^ ((j & 7) << 3))];
                    #pragma unroll
                    for (int rp = 0; rp < 2; ++rp)
                        acc2[s][rp][cb] = __builtin_amdgcn_mfma_f32_16x16x32_bf16(a[rp], bb, acc2[s][rp][cb], 0, 0, 0);
                }
        }
    }

    // ---- reduce ||M_s||_F^2
    {
        float ps0 = 0.f, ps1 = 0.f;
        #pragma unroll
        for (int rp = 0; rp < 2; ++rp)
            #pragma unroll
            for (int cb = 0; cb < 4; ++cb) {
                const f32x4 a0 = acc2[0][rp][cb], a1 = acc2[1][rp][cb];
                ps0 = fmaf(a0.x, a0.x, ps0); ps0 = fmaf(a0.y, a0.y, ps0);
                ps0 = fmaf(a0.z, a0.z, ps0); ps0 = fmaf(a0.w, a0.w, ps0);
                ps1 = fmaf(a1.x, a1.x, ps1); ps1 = fmaf(a1.y, a1.y, ps1);
                ps1 = fmaf(a1.z, a1.z, ps1); ps1 = fmaf(a1.w, a1.w, ps1);
            }
        #pragma unroll
        for (int off = 32; off > 0; off >>= 1) {
            ps0 += __shfl_down(ps0, off, 64);
            ps1 += __shfl_down(ps1, off, 64);
        }
        if (l == 0) { red[0][w] = ps0; red[1][w] = ps1; }
    }
    __syncthreads();

    if (t < 128) {
        const int s = t >> 6, j = t & 63;
        float S = 0.f;
        #pragma unroll
        for (int i = 0; i < 8; ++i) S += red[s][i];
        const float* fws = (const float*)(ws + F_OFF);
        const float f = fws[(size_t)(b * 2 + s) * 64 + j];
        const float kv = kp[0];
        const float ksp = fmaxf(kv, 0.0f) + log1pf(expf(-fabsf(kv)));
        out[(size_t)(b * 2 + s) * 64 + j] = tanhf(ksp * f / (sqrtf(S) + 1e-4f));
    }
}

extern "C" void kernel_launch(void* const* d_in, const int* in_sizes, int n_in,
                              void* d_out, int out_size, void* d_ws, size_t ws_size,
                              hipStream_t stream) {
    const float* x  = (const float*)d_in[0];
    const float* W1 = (const float*)d_in[1];
    const float* b1 = (const float*)d_in[2];
    const float* W2 = (const float*)d_in[3];
    const float* b2 = (const float*)d_in[4];
    const float* W3 = (const float*)d_in[5];
    const float* b3 = (const float*)d_in[6];
    const float* kp = (const float*)d_in[7];
    char* ws = (char*)d_ws;

    k0_prep<<<72, 256, 0, stream>>>(W1, W2, W3, ws);
    k1_forward<<<512, 256, 0, stream>>>(x, W1, b1, W2, b2, W3, b3, ws);
    k2_jac<<<4096, 512, 0, stream>>>(ws, kp, (float*)d_out);
}